// Round 3
// baseline (767.414 us; speedup 1.0000x reference)
//
#include <hip/hip_runtime.h>

typedef unsigned short u16;
typedef __bf16 bf16x8 __attribute__((ext_vector_type(8)));
typedef float f32x4 __attribute__((ext_vector_type(4)));
typedef unsigned int u32x4 __attribute__((ext_vector_type(4)));

// RTNE float -> bf16 (finite inputs only)
__device__ __forceinline__ u16 f2b(float f) {
    union { float f; unsigned u; } c; c.f = f;
    unsigned r = (c.u + 0x7fffu + ((c.u >> 16) & 1u)) >> 16;
    return (u16)r;
}

__device__ __forceinline__ bf16x8 ldlds(const u16* p) {
    return __builtin_bit_cast(bf16x8, *(const u32x4*)p);
}

// stage 8 contiguous elements into LDS as bf16 (fp32 source converts on the fly)
__device__ __forceinline__ void stage8(const float* s, u16* d) {
    float4 a = *(const float4*)s;
    float4 b = *(const float4*)(s + 4);
    ushort4 lo; lo.x = f2b(a.x); lo.y = f2b(a.y); lo.z = f2b(a.z); lo.w = f2b(a.w);
    ushort4 hi; hi.x = f2b(b.x); hi.y = f2b(b.y); hi.z = f2b(b.z); hi.w = f2b(b.w);
    *(ushort4*)d = lo;
    *(ushort4*)(d + 4) = hi;
}
__device__ __forceinline__ void stage8(const u16* s, u16* d) {
    *(u32x4*)d = *(const u32x4*)s;
}

// C-store: bf16 or fp32 depending on destination type
__device__ __forceinline__ void cstore(float v, u16* p) { *p = f2b(v); }
__device__ __forceinline__ void cstore(float v, float* p) { *p = v; }

// ---------------------------------------------------------------------------
// fp32 -> bf16 bulk convert, 8 elems/thread. Used once per input tensor so the
// GEMM staging path is pure b128 copies (no per-K-step f2b VALU work).
// ---------------------------------------------------------------------------
__global__ __launch_bounds__(256) void cvt_bf16(
    const float* __restrict__ in, u16* __restrict__ out, int n8)
{
    int i = blockIdx.x * 256 + threadIdx.x;
    if (i >= n8) return;
    const float* s = in + (size_t)i * 8;
    float4 a = *(const float4*)s;
    float4 b = *(const float4*)(s + 4);
    ushort4 lo; lo.x = f2b(a.x); lo.y = f2b(a.y); lo.z = f2b(a.z); lo.w = f2b(a.w);
    ushort4 hi; hi.x = f2b(b.x); hi.y = f2b(b.y); hi.z = f2b(b.z); hi.w = f2b(b.w);
    u16* d = out + (size_t)i * 8;
    *(ushort4*)d = lo;
    *(ushort4*)(d + 4) = hi;
}

// ---------------------------------------------------------------------------
// C[m][n] = sum_k A[m][k]*B[n][k] (+bias[n]); A: MxK row-major (fp32 or bf16),
// B: NxK row-major (fp32 or bf16), C bf16 or fp32. Tile 128x64, BK=32,
// 4 waves (2x2). LDS stride 40 u16 (80 B): 16B-aligned ds_read_b128,
// benign 2-way conflicts. fp32 sources round to bf16 during staging.
// T1 XCD swizzle: each XCD owns a contiguous chunk of tiles covering 4
// M-panels x all N-tiles (3 MB L2 footprint) so A panels are fetched once.
// ---------------------------------------------------------------------------
template <typename TA, typename TB, typename TC>
__global__ __launch_bounds__(256) void gemm_bt(
    const TA* __restrict__ A, const TB* __restrict__ Bm,
    const float* __restrict__ bias, TC* __restrict__ C,
    int M, int N, int K)
{
    __shared__ u16 As[128 * 40];
    __shared__ u16 Bs[64 * 40];
    const int tid = threadIdx.x;
    const int wave = tid >> 6, lane = tid & 63, lq = lane >> 4, l15 = lane & 15;
    const int wr = wave >> 1, wc = wave & 1;

    // XCD-aware remap (grid is (M/128, N/64); nwg % 8 == 0 for all our shapes)
    const int hwid = blockIdx.y * gridDim.x + blockIdx.x;
    const int nwg = gridDim.x * gridDim.y;
    const int swz = (hwid & 7) * (nwg >> 3) + (hwid >> 3);
    const int tx = swz / gridDim.y;   // M-tile (few per XCD chunk)
    const int ty = swz % gridDim.y;   // N-tile (all per XCD chunk)
    const size_t m0 = (size_t)tx * 128, n0 = (size_t)ty * 64;

    f32x4 acc[4][2];
#pragma unroll
    for (int i = 0; i < 4; ++i)
#pragma unroll
        for (int j = 0; j < 2; ++j) acc[i][j] = (f32x4){0.f, 0.f, 0.f, 0.f};

    for (int k0 = 0; k0 < K; k0 += 32) {
#pragma unroll
        for (int g = 0; g < 2; ++g) {
            int c = tid + g * 256;
            int row = c >> 2, col8 = (c & 3) * 8;
            stage8(&A[(m0 + row) * (size_t)K + k0 + col8], &As[row * 40 + col8]);
        }
        {
            int row = tid >> 2, col8 = (tid & 3) * 8;
            stage8(&Bm[(n0 + row) * (size_t)K + k0 + col8], &Bs[row * 40 + col8]);
        }
        __syncthreads();
        bf16x8 af[4], bfr[2];
#pragma unroll
        for (int i = 0; i < 4; ++i)
            af[i] = ldlds(&As[(wr * 64 + i * 16 + l15) * 40 + lq * 8]);
#pragma unroll
        for (int j = 0; j < 2; ++j)
            bfr[j] = ldlds(&Bs[(wc * 32 + j * 16 + l15) * 40 + lq * 8]);
#pragma unroll
        for (int i = 0; i < 4; ++i)
#pragma unroll
            for (int j = 0; j < 2; ++j)
                acc[i][j] = __builtin_amdgcn_mfma_f32_16x16x32_bf16(
                    af[i], bfr[j], acc[i][j], 0, 0, 0);
        __syncthreads();
    }
    // epilogue: C/D layout col=lane&15 (n), row=(lane>>4)*4+reg (m)
#pragma unroll
    for (int j = 0; j < 2; ++j) {
        int n = (int)n0 + wc * 32 + j * 16 + l15;
        float bv = bias ? bias[n] : 0.0f;
#pragma unroll
        for (int i = 0; i < 4; ++i) {
            int mb = (int)m0 + wr * 64 + i * 16 + lq * 4;
#pragma unroll
            for (int r = 0; r < 4; ++r)
                cstore(acc[i][j][r] + bv, &C[(size_t)(mb + r) * N + n]);
        }
    }
}

// ---------------------------------------------------------------------------
// Fused attention: one block per (b, h, 64-query tile). 4 waves; wave w owns
// query rows w*16..w*16+15. Writes scaled S tiles (fp32, nontemporal) to qk
// output, online softmax, PV accumulate, writes wv (bf16, (b,ctx,h*64+d)).
// LDS row stride 72 u16 (144 B): 16B-aligned b128 frags, 2-way conflicts.
// K/V staging is async-split (T14): next tile's global loads issue BEFORE the
// compute phase; the LDS writes land after the post-compute barrier, so HBM/L2
// latency hides under S/softmax/PV instead of sitting between two barriers.
// T1 XCD swizzle: each XCD owns 4 whole (b,h) groups (2 MB K/V, L2-fit) so
// K/V panels are fetched from HBM once instead of by all 8 XCDs.
// ---------------------------------------------------------------------------
__global__ __launch_bounds__(256) void attn_kernel(
    const u16* __restrict__ qb, const u16* __restrict__ kb,
    const u16* __restrict__ vb, const float* __restrict__ factor,
    float* __restrict__ qk_out, u16* __restrict__ wv_out)
{
    const int SCTX = 2048, SD = 1024;
    __shared__ u16 qs[64 * 72];
    __shared__ u16 ks[64 * 72];
    __shared__ u16 vts[64 * 72];  // transposed: [dim][key]
    __shared__ u16 ps[64 * 72];
    __shared__ float zf[64];

    const int tid = threadIdx.x;
    const int wave = tid >> 6, lane = tid & 63, lq = lane >> 4, l15 = lane & 15;

    // XCD-aware remap: grid (32,16,2) = 1024 blocks, chunks of 128 per XCD
    const int hwid = (blockIdx.z * gridDim.y + blockIdx.y) * gridDim.x + blockIdx.x;
    const int swz = (hwid & 7) * 128 + (hwid >> 3);
    const int q0 = (swz & 31) * 64, h = (swz >> 5) & 15, b = swz >> 9;

    float zfac = log1pf(expf(factor[0]));
    zfac = fminf(fmaxf(zfac, 0.0f), 0.001f);

    // staging geometry (constant per thread)
    const int srow = tid >> 3, scol = (tid & 7) * 8;        // k rows srow, srow+32
    const int vkrow = tid & 63, vd0 = ((tid >> 6) & 7) * 8; // v dims vd0, vd0+32

    const size_t qbase = ((size_t)(b * SCTX + q0)) * SD + h * 64;
#pragma unroll
    for (int g = 0; g < 2; ++g) {
        int row = srow + g * 32;
        *(u32x4*)&qs[row * 72 + scol] =
            *(const u32x4*)&qb[qbase + (size_t)row * SD + scol];
    }
    // stage tile 0 of k/v/zf directly
    {
        const size_t kbase = ((size_t)(b * SCTX)) * SD + h * 64;
#pragma unroll
        for (int g = 0; g < 2; ++g) {
            int row = srow + g * 32;
            *(u32x4*)&ks[row * 72 + scol] =
                *(const u32x4*)&kb[kbase + (size_t)row * SD + scol];
        }
#pragma unroll
        for (int g = 0; g < 2; ++g) {
            int d8 = vd0 + g * 32;
            u32x4 vv = *(const u32x4*)&vb[kbase + (size_t)vkrow * SD + d8];
#pragma unroll
            for (int j = 0; j < 8; ++j) {
                unsigned uu = vv[j >> 1];
                u16 e = (j & 1) ? (u16)(uu >> 16) : (u16)(uu & 0xffffu);
                vts[(d8 + j) * 72 + vkrow] = e;  // bank = vkrow>>1: 2-way, free
            }
        }
        if (tid < 64) {
            u16 k0v = kb[kbase + (size_t)tid * SD];  // head-dim 0 of key
            zf[tid] = ((k0v & 0x7fffu) == 0) ? zfac : 1.0f;  // catches -0 too
        }
    }
    __syncthreads();
    // q A-fragments are loop-invariant: hoist
    bf16x8 aq0 = ldlds(&qs[(wave * 16 + l15) * 72 + lq * 8]);
    bf16x8 aq1 = ldlds(&qs[(wave * 16 + l15) * 72 + lq * 8 + 32]);

    f32x4 oacc[4];
#pragma unroll
    for (int t = 0; t < 4; ++t) oacc[t] = (f32x4){0.f, 0.f, 0.f, 0.f};
    float mrun[4], lrun[4];
#pragma unroll
    for (int r = 0; r < 4; ++r) { mrun[r] = -3.0e38f; lrun[r] = 0.0f; }

    const size_t qkrow0 = ((size_t)((b * 16 + h) * SCTX + q0)) * SCTX;

    for (int kt = 0; kt < 32; ++kt) {
        // ---- issue next tile's global loads (registers) before compute ----
        u32x4 pk0, pk1, pv0, pv1; u16 pz = 0;
        const bool pre = (kt + 1 < 32);
        if (pre) {
            const size_t kb1 = ((size_t)(b * SCTX + (kt + 1) * 64)) * SD + h * 64;
            pk0 = *(const u32x4*)&kb[kb1 + (size_t)srow * SD + scol];
            pk1 = *(const u32x4*)&kb[kb1 + (size_t)(srow + 32) * SD + scol];
            pv0 = *(const u32x4*)&vb[kb1 + (size_t)vkrow * SD + vd0];
            pv1 = *(const u32x4*)&vb[kb1 + (size_t)vkrow * SD + vd0 + 32];
            if (tid < 64) pz = kb[kb1 + (size_t)tid * SD];
        }

        // ---- S = q . k^T over hd=64 (2 MFMAs per 16x16 tile) ----
        f32x4 sacc[4];
#pragma unroll
        for (int t = 0; t < 4; ++t) sacc[t] = (f32x4){0.f, 0.f, 0.f, 0.f};
#pragma unroll
        for (int t = 0; t < 4; ++t) {
            bf16x8 bk0 = ldlds(&ks[(t * 16 + l15) * 72 + lq * 8]);
            bf16x8 bk1 = ldlds(&ks[(t * 16 + l15) * 72 + lq * 8 + 32]);
            sacc[t] = __builtin_amdgcn_mfma_f32_16x16x32_bf16(aq0, bk0, sacc[t], 0, 0, 0);
            sacc[t] = __builtin_amdgcn_mfma_f32_16x16x32_bf16(aq1, bk1, sacc[t], 0, 0, 0);
        }
        // scale^2 = (hd^-0.25)^2 = 0.125, times per-key zero factor
        float zfc[4];
#pragma unroll
        for (int t = 0; t < 4; ++t) zfc[t] = zf[t * 16 + l15] * 0.125f;
#pragma unroll
        for (int t = 0; t < 4; ++t)
#pragma unroll
            for (int r = 0; r < 4; ++r) sacc[t][r] *= zfc[t];
        // store qk tile (fp32 output; streamed, never re-read -> nontemporal)
#pragma unroll
        for (int t = 0; t < 4; ++t)
#pragma unroll
            for (int r = 0; r < 4; ++r) {
                int row = wave * 16 + lq * 4 + r;
                __builtin_nontemporal_store(sacc[t][r],
                    &qk_out[qkrow0 + (size_t)row * SCTX + kt * 64 + t * 16 + l15]);
            }
        // online softmax per accumulator row r (rows lq*4+r; reduce over l15)
#pragma unroll
        for (int r = 0; r < 4; ++r) {
            float mx = fmaxf(fmaxf(sacc[0][r], sacc[1][r]),
                             fmaxf(sacc[2][r], sacc[3][r]));
            mx = fmaxf(mx, __shfl_xor(mx, 1, 64));
            mx = fmaxf(mx, __shfl_xor(mx, 2, 64));
            mx = fmaxf(mx, __shfl_xor(mx, 4, 64));
            mx = fmaxf(mx, __shfl_xor(mx, 8, 64));
            float mnew = fmaxf(mrun[r], mx);
            float alpha = __expf(mrun[r] - mnew);
            float p0 = __expf(sacc[0][r] - mnew);
            float p1 = __expf(sacc[1][r] - mnew);
            float p2 = __expf(sacc[2][r] - mnew);
            float p3 = __expf(sacc[3][r] - mnew);
            float rs = p0 + p1 + p2 + p3;
            rs += __shfl_xor(rs, 1, 64);
            rs += __shfl_xor(rs, 2, 64);
            rs += __shfl_xor(rs, 4, 64);
            rs += __shfl_xor(rs, 8, 64);
            lrun[r] = lrun[r] * alpha + rs;
            mrun[r] = mnew;
            int prow = (wave * 16 + lq * 4 + r) * 72;
            ps[prow + 0 + l15] = f2b(p0);
            ps[prow + 16 + l15] = f2b(p1);
            ps[prow + 32 + l15] = f2b(p2);
            ps[prow + 48 + l15] = f2b(p3);
#pragma unroll
            for (int td = 0; td < 4; ++td) oacc[td][r] *= alpha;
        }
        // PV: P (wave-private rows) as A-operand, V^T rows as B-operand
        bf16x8 ap0 = ldlds(&ps[(wave * 16 + l15) * 72 + lq * 8]);
        bf16x8 ap1 = ldlds(&ps[(wave * 16 + l15) * 72 + lq * 8 + 32]);
#pragma unroll
        for (int td = 0; td < 4; ++td) {
            bf16x8 bv0 = ldlds(&vts[(td * 16 + l15) * 72 + lq * 8]);
            bf16x8 bv1 = ldlds(&vts[(td * 16 + l15) * 72 + lq * 8 + 32]);
            oacc[td] = __builtin_amdgcn_mfma_f32_16x16x32_bf16(ap0, bv0, oacc[td], 0, 0, 0);
            oacc[td] = __builtin_amdgcn_mfma_f32_16x16x32_bf16(ap1, bv1, oacc[td], 0, 0, 0);
        }

        __syncthreads();  // all waves done reading ks/vts/zf
        if (pre) {
            // write prefetched regs -> LDS (compiler waits vmcnt for the regs)
            *(u32x4*)&ks[srow * 72 + scol] = pk0;
            *(u32x4*)&ks[(srow + 32) * 72 + scol] = pk1;
#pragma unroll
            for (int j = 0; j < 8; ++j) {
                unsigned uu = pv0[j >> 1];
                u16 e = (j & 1) ? (u16)(uu >> 16) : (u16)(uu & 0xffffu);
                vts[(vd0 + j) * 72 + vkrow] = e;
            }
#pragma unroll
            for (int j = 0; j < 8; ++j) {
                unsigned uu = pv1[j >> 1];
                u16 e = (j & 1) ? (u16)(uu >> 16) : (u16)(uu & 0xffffu);
                vts[(vd0 + 32 + j) * 72 + vkrow] = e;
            }
            if (tid < 64) zf[tid] = ((pz & 0x7fffu) == 0) ? zfac : 1.0f;
            __syncthreads();  // stage complete
        }
    }
    float linv[4];
#pragma unroll
    for (int r = 0; r < 4; ++r) linv[r] = 1.0f / lrun[r];
#pragma unroll
    for (int td = 0; td < 4; ++td)
#pragma unroll
        for (int r = 0; r < 4; ++r) {
            int row = wave * 16 + lq * 4 + r;
            wv_out[qbase + (size_t)row * SD + td * 16 + l15] =
                f2b(oacc[td][r] * linv[r]);
        }
}

// ---------------------------------------------------------------------------
// d_out is FP32 (reference output dtype): out (2,2048,1024) then qk
// (2,16,2048,2048). Internal compute is bf16 MFMA (threshold 0.055 is an
// 8x-bf16-eps floor — generous). Workspace: q/k/v (25.2 MB) + optional bf16
// Wout copy (2 MB, gated on ws_size). wv (bf16) stages in d_out's first
// 8.4 MB — overwritten only by the final projection, whose input (out1) lives
// in qbuf by then. bf16 copies of x/Wq/Wk/Wv stage in d_out's qk region
// (consumed by the QKV GEMMs before attn writes qk).
// ---------------------------------------------------------------------------
extern "C" void kernel_launch(void* const* d_in, const int* in_sizes, int n_in,
                              void* d_out, int out_size, void* d_ws, size_t ws_size,
                              hipStream_t stream)
{
    (void)in_sizes; (void)n_in; (void)out_size;
    const float* x      = (const float*)d_in[0];
    const float* Wq     = (const float*)d_in[1];
    const float* bq     = (const float*)d_in[2];
    const float* Wk     = (const float*)d_in[3];
    const float* Wv     = (const float*)d_in[4];
    const float* bvv    = (const float*)d_in[5];
    const float* Wout   = (const float*)d_in[6];
    const float* bout   = (const float*)d_in[7];
    const float* factor = (const float*)d_in[8];

    u16* ws   = (u16*)d_ws;
    u16* qbuf = ws;                 // 4194304 u16 each
    u16* kbuf = ws + 4194304;
    u16* vbuf = ws + 8388608;       // q/k/v end at byte 25,165,824
    u16* woutb = ws + 12582912;     // optional bf16 Wout (needs +2 MB)
    const bool have_woutb = ws_size >= (size_t)27262976;

    float* outp = (float*)d_out;    // fp32 out (2,2048,1024)
    float* qkp  = outp + 4194304;   // fp32 qk (2,16,2048,2048)
    u16* wvo  = (u16*)d_out;        // attention wv staged here (bf16 temp)
    u16* out1 = qbuf;               // first projection result (bf16 temp)

    // bf16 input copies staged in the (not-yet-written) qk region of d_out
    u16* xb  = (u16*)qkp;           // 4194304 u16 (8.4 MB)
    u16* wqb = xb  + 4194304;       // 1048576 u16 each
    u16* wkb = wqb + 1048576;
    u16* wvb = wkb + 1048576;

    cvt_bf16<<<2048, 256, 0, stream>>>(x,  xb,  524288);
    cvt_bf16<<<512,  256, 0, stream>>>(Wq, wqb, 131072);
    cvt_bf16<<<512,  256, 0, stream>>>(Wk, wkb, 131072);
    cvt_bf16<<<512,  256, 0, stream>>>(Wv, wvb, 131072);
    if (have_woutb)
        cvt_bf16<<<512, 256, 0, stream>>>(Wout, woutb, 131072);

    dim3 gg(32, 16);  // M/128 x N/64

    gemm_bt<u16, u16, u16><<<gg, 256, 0, stream>>>(xb, wqb, bq,      qbuf, 4096, 1024, 1024);
    gemm_bt<u16, u16, u16><<<gg, 256, 0, stream>>>(xb, wkb, nullptr, kbuf, 4096, 1024, 1024);
    gemm_bt<u16, u16, u16><<<gg, 256, 0, stream>>>(xb, wvb, bvv,     vbuf, 4096, 1024, 1024);

    attn_kernel<<<dim3(32, 16, 2), 256, 0, stream>>>(qbuf, kbuf, vbuf, factor, qkp, wvo);

    if (have_woutb) {
        gemm_bt<u16, u16, u16><<<gg, 256, 0, stream>>>(wvo,  woutb, bout, out1, 4096, 1024, 1024);
        gemm_bt<u16, u16, float><<<gg, 256, 0, stream>>>(out1, woutb, bout, outp, 4096, 1024, 1024);
    } else {
        gemm_bt<u16, float, u16><<<gg, 256, 0, stream>>>(wvo,  Wout, bout, out1, 4096, 1024, 1024);
        gemm_bt<u16, float, float><<<gg, 256, 0, stream>>>(out1, Wout, bout, outp, 4096, 1024, 1024);
    }
}

// Round 4
// 751.450 us; speedup vs baseline: 1.0212x; 1.0212x over previous
//
#include <hip/hip_runtime.h>

typedef unsigned short u16;
typedef __bf16 bf16x8 __attribute__((ext_vector_type(8)));
typedef float f32x4 __attribute__((ext_vector_type(4)));
typedef unsigned int u32x4 __attribute__((ext_vector_type(4)));

// RTNE float -> bf16 (finite inputs only)
__device__ __forceinline__ u16 f2b(float f) {
    union { float f; unsigned u; } c; c.f = f;
    unsigned r = (c.u + 0x7fffu + ((c.u >> 16) & 1u)) >> 16;
    return (u16)r;
}

__device__ __forceinline__ bf16x8 ldlds(const u16* p) {
    return __builtin_bit_cast(bf16x8, *(const u32x4*)p);
}

// async global->LDS, 16B per lane; dest = wave-uniform base + lane*16 (m104)
__device__ __forceinline__ void glds16(const u16* g, u16* l) {
    __builtin_amdgcn_global_load_lds(
        (const __attribute__((address_space(1))) unsigned*)g,
        (__attribute__((address_space(3))) unsigned*)l, 16, 0, 0);
}

// stage 8 contiguous elements into LDS as bf16 (fp32 source converts on the fly)
__device__ __forceinline__ void stage8(const float* s, u16* d) {
    float4 a = *(const float4*)s;
    float4 b = *(const float4*)(s + 4);
    ushort4 lo; lo.x = f2b(a.x); lo.y = f2b(a.y); lo.z = f2b(a.z); lo.w = f2b(a.w);
    ushort4 hi; hi.x = f2b(b.x); hi.y = f2b(b.y); hi.z = f2b(b.z); hi.w = f2b(b.w);
    *(ushort4*)d = lo;
    *(ushort4*)(d + 4) = hi;
}
__device__ __forceinline__ void stage8(const u16* s, u16* d) {
    *(u32x4*)d = *(const u32x4*)s;
}

// C-store: bf16 or fp32 depending on destination type
__device__ __forceinline__ void cstore(float v, u16* p) { *p = f2b(v); }
__device__ __forceinline__ void cstore(float v, float* p) { *p = v; }

// ---------------------------------------------------------------------------
// Fused fp32->bf16 conversion of x, Wq, Wk, Wv, Wout in ONE launch.
// Group i handles 8 contiguous elements of its tensor.
// ---------------------------------------------------------------------------
__global__ __launch_bounds__(256) void cvt_all(
    const float* __restrict__ x,  const float* __restrict__ wq,
    const float* __restrict__ wk, const float* __restrict__ wv,
    const float* __restrict__ wo,
    u16* __restrict__ xb, u16* __restrict__ wqb, u16* __restrict__ wkb,
    u16* __restrict__ wvb, u16* __restrict__ wob)
{
    int i = blockIdx.x * 256 + threadIdx.x;   // grid covers 1048576 groups
    const float* s; u16* d; int off;
    if (i < 524288)      { s = x;  d = xb;  off = i; }
    else if (i < 655360) { s = wq; d = wqb; off = i - 524288; }
    else if (i < 786432) { s = wk; d = wkb; off = i - 655360; }
    else if (i < 917504) { s = wv; d = wvb; off = i - 786432; }
    else                 { s = wo; d = wob; off = i - 917504; }
    const float* sp = s + (size_t)off * 8;
    float4 a = *(const float4*)sp;
    float4 b = *(const float4*)(sp + 4);
    ushort4 lo; lo.x = f2b(a.x); lo.y = f2b(a.y); lo.z = f2b(a.z); lo.w = f2b(a.w);
    ushort4 hi; hi.x = f2b(b.x); hi.y = f2b(b.y); hi.z = f2b(b.z); hi.w = f2b(b.w);
    u16* dp = d + (size_t)off * 8;
    *(ushort4*)dp = lo;
    *(ushort4*)(dp + 4) = hi;
}

// ---------------------------------------------------------------------------
// Transposing fp32->bf16 convert: out[j][i] = bf16(in[i][j]), 1024x1024.
// 32x32 LDS tile, +1 pad. grid (32,32).
// ---------------------------------------------------------------------------
__global__ __launch_bounds__(256) void cvt_bf16_t(
    const float* __restrict__ in, u16* __restrict__ out)
{
    __shared__ float t[32][33];
    const int i0 = blockIdx.x * 32, j0 = blockIdx.y * 32;
    const int r = threadIdx.x >> 3, c4 = (threadIdx.x & 7) * 4;
    float4 v = *(const float4*)&in[(size_t)(i0 + r) * 1024 + j0 + c4];
    t[r][c4] = v.x; t[r][c4 + 1] = v.y; t[r][c4 + 2] = v.z; t[r][c4 + 3] = v.w;
    __syncthreads();
    ushort4 o;
    o.x = f2b(t[c4][r]);     o.y = f2b(t[c4 + 1][r]);
    o.z = f2b(t[c4 + 2][r]); o.w = f2b(t[c4 + 3][r]);
    *(ushort4*)&out[(size_t)(j0 + r) * 1024 + i0 + c4] = o;
}

// ---------------------------------------------------------------------------
// b2[n] = sum_j Wout[n][j]*bout[j] + bout[n]  (fp32, exact weights)
// one 64-lane block per n.
// ---------------------------------------------------------------------------
__global__ __launch_bounds__(64) void bias2_kernel(
    const float* __restrict__ W, const float* __restrict__ b,
    float* __restrict__ b2)
{
    const int n = blockIdx.x, l = threadIdx.x;
    float s = 0.0f;
    for (int j = l; j < 1024; j += 64) s += W[(size_t)n * 1024 + j] * b[j];
#pragma unroll
    for (int o = 1; o < 64; o <<= 1) s += __shfl_xor(s, o, 64);
    if (l == 0) b2[n] = s + b[n];
}

// ---------------------------------------------------------------------------
// bf16 x bf16 GEMM with global_load_lds staging (m97-style).
// C[m][n] = sum_k A[m][k]*B[n][k] (+bias[n]). Tile 128x64, BK=32, 4 waves.
// LDS is LINEAR [row][32] u16 (glds needs lane-linear dest, m104); bank
// conflicts on the b128 fragment reads are avoided by the XOR source-swizzle
// (rule #21): LDS (row, c) holds A[row][c ^ ((row>>1)&3)]; reads apply the
// same XOR -> 2-way conflict only (free, m136).
// ---------------------------------------------------------------------------
template <typename TC>
__global__ __launch_bounds__(256) void gemm_bt_gl(
    const u16* __restrict__ A, const u16* __restrict__ Bm,
    const float* __restrict__ bias, TC* __restrict__ C,
    int M, int N, int K)
{
    __shared__ __align__(16) u16 As[128 * 32];
    __shared__ __align__(16) u16 Bs[64 * 32];
    const int tid = threadIdx.x;
    const int wave = tid >> 6, lane = tid & 63, lq = lane >> 4, l15 = lane & 15;
    const int wr = wave >> 1, wc = wave & 1;

    // XCD-aware remap (nwg % 8 == 0 for all our shapes)
    const int hwid = blockIdx.y * gridDim.x + blockIdx.x;
    const int nwg = gridDim.x * gridDim.y;
    const int swz = (hwid & 7) * (nwg >> 3) + (hwid >> 3);
    const int tx = swz / gridDim.y, ty = swz % gridDim.y;
    const size_t m0 = (size_t)tx * 128, n0 = (size_t)ty * 64;

    // staging: lane l of issue (wave,g) covers row (wave*2+g)*16 + (l>>2),
    // LDS chunk col c_lds = l&3; source col = c_lds ^ ((row>>1)&3), which
    // reduces to the lane-only expression (l&3)^((l>>3)&3).
    const int csrc = ((lane & 3) ^ ((lane >> 3) & 3)) * 8;   // elem offset
    const int arow0 = wave * 32 + (lane >> 2);
    const int brow = wave * 16 + (lane >> 2);
    const u16* pa0 = A + (m0 + arow0) * (size_t)K + csrc;
    const u16* pa1 = A + (m0 + arow0 + 16) * (size_t)K + csrc;
    const u16* pb = Bm + (n0 + brow) * (size_t)K + csrc;
    u16* la0 = &As[wave * 1024];
    u16* la1 = &As[wave * 1024 + 512];
    u16* lb = &Bs[wave * 512];

    f32x4 acc[4][2];
#pragma unroll
    for (int i = 0; i < 4; ++i)
#pragma unroll
        for (int j = 0; j < 2; ++j) acc[i][j] = (f32x4){0.f, 0.f, 0.f, 0.f};

    const int sx = (lq ^ ((l15 >> 1) & 3)) * 8;   // swizzled read col (u16)

    for (int k0 = 0; k0 < K; k0 += 32) {
        glds16(pa0, la0);
        glds16(pa1, la1);
        glds16(pb, lb);
        pa0 += 32; pa1 += 32; pb += 32;
        __syncthreads();   // drains vmcnt -> LDS tiles valid
        bf16x8 af[4], bfr[2];
#pragma unroll
        for (int i = 0; i < 4; ++i)
            af[i] = ldlds(&As[(wr * 64 + i * 16 + l15) * 32 + sx]);
#pragma unroll
        for (int j = 0; j < 2; ++j)
            bfr[j] = ldlds(&Bs[(wc * 32 + j * 16 + l15) * 32 + sx]);
#pragma unroll
        for (int i = 0; i < 4; ++i)
#pragma unroll
            for (int j = 0; j < 2; ++j)
                acc[i][j] = __builtin_amdgcn_mfma_f32_16x16x32_bf16(
                    af[i], bfr[j], acc[i][j], 0, 0, 0);
        __syncthreads();
    }
    // epilogue: C/D layout col=lane&15 (n), row=(lane>>4)*4+reg (m)
#pragma unroll
    for (int j = 0; j < 2; ++j) {
        int n = (int)n0 + wc * 32 + j * 16 + l15;
        float bv = bias ? bias[n] : 0.0f;
#pragma unroll
        for (int i = 0; i < 4; ++i) {
            int mb = (int)m0 + wr * 64 + i * 16 + lq * 4;
#pragma unroll
            for (int r = 0; r < 4; ++r)
                cstore(acc[i][j][r] + bv, &C[(size_t)(mb + r) * N + n]);
        }
    }
}

// ---------------------------------------------------------------------------
// Mixed-dtype GEMM (kept for the fp32-Wout fallback). Tile 128x64, BK=32,
// reg staging, LDS stride 40 u16.
// ---------------------------------------------------------------------------
template <typename TA, typename TB, typename TC>
__global__ __launch_bounds__(256) void gemm_bt(
    const TA* __restrict__ A, const TB* __restrict__ Bm,
    const float* __restrict__ bias, TC* __restrict__ C,
    int M, int N, int K)
{
    __shared__ __align__(16) u16 As[128 * 40];
    __shared__ __align__(16) u16 Bs[64 * 40];
    const int tid = threadIdx.x;
    const int wave = tid >> 6, lane = tid & 63, lq = lane >> 4, l15 = lane & 15;
    const int wr = wave >> 1, wc = wave & 1;

    const int hwid = blockIdx.y * gridDim.x + blockIdx.x;
    const int nwg = gridDim.x * gridDim.y;
    const int swz = (hwid & 7) * (nwg >> 3) + (hwid >> 3);
    const int tx = swz / gridDim.y, ty = swz % gridDim.y;
    const size_t m0 = (size_t)tx * 128, n0 = (size_t)ty * 64;

    f32x4 acc[4][2];
#pragma unroll
    for (int i = 0; i < 4; ++i)
#pragma unroll
        for (int j = 0; j < 2; ++j) acc[i][j] = (f32x4){0.f, 0.f, 0.f, 0.f};

    for (int k0 = 0; k0 < K; k0 += 32) {
#pragma unroll
        for (int g = 0; g < 2; ++g) {
            int c = tid + g * 256;
            int row = c >> 2, col8 = (c & 3) * 8;
            stage8(&A[(m0 + row) * (size_t)K + k0 + col8], &As[row * 40 + col8]);
        }
        {
            int row = tid >> 2, col8 = (tid & 3) * 8;
            stage8(&Bm[(n0 + row) * (size_t)K + k0 + col8], &Bs[row * 40 + col8]);
        }
        __syncthreads();
        bf16x8 af[4], bfr[2];
#pragma unroll
        for (int i = 0; i < 4; ++i)
            af[i] = ldlds(&As[(wr * 64 + i * 16 + l15) * 40 + lq * 8]);
#pragma unroll
        for (int j = 0; j < 2; ++j)
            bfr[j] = ldlds(&Bs[(wc * 32 + j * 16 + l15) * 40 + lq * 8]);
#pragma unroll
        for (int i = 0; i < 4; ++i)
#pragma unroll
            for (int j = 0; j < 2; ++j)
                acc[i][j] = __builtin_amdgcn_mfma_f32_16x16x32_bf16(
                    af[i], bfr[j], acc[i][j], 0, 0, 0);
        __syncthreads();
    }
#pragma unroll
    for (int j = 0; j < 2; ++j) {
        int n = (int)n0 + wc * 32 + j * 16 + l15;
        float bv = bias ? bias[n] : 0.0f;
#pragma unroll
        for (int i = 0; i < 4; ++i) {
            int mb = (int)m0 + wr * 64 + i * 16 + lq * 4;
#pragma unroll
            for (int r = 0; r < 4; ++r)
                cstore(acc[i][j][r] + bv, &C[(size_t)(mb + r) * N + n]);
        }
    }
}

// ---------------------------------------------------------------------------
// Fused attention (unchanged from R3 — passed). One block per (b,h,64-q tile).
// Async-split K/V staging (T14), nontemporal fp32 qk stores, XCD swizzle.
// ---------------------------------------------------------------------------
__global__ __launch_bounds__(256) void attn_kernel(
    const u16* __restrict__ qb, const u16* __restrict__ kb,
    const u16* __restrict__ vb, const float* __restrict__ factor,
    float* __restrict__ qk_out, u16* __restrict__ wv_out)
{
    const int SCTX = 2048, SD = 1024;
    __shared__ __align__(16) u16 qs[64 * 72];
    __shared__ __align__(16) u16 ks[64 * 72];
    __shared__ __align__(16) u16 vts[64 * 72];  // transposed: [dim][key]
    __shared__ __align__(16) u16 ps[64 * 72];
    __shared__ float zf[64];

    const int tid = threadIdx.x;
    const int wave = tid >> 6, lane = tid & 63, lq = lane >> 4, l15 = lane & 15;

    const int hwid = (blockIdx.z * gridDim.y + blockIdx.y) * gridDim.x + blockIdx.x;
    const int swz = (hwid & 7) * 128 + (hwid >> 3);
    const int q0 = (swz & 31) * 64, h = (swz >> 5) & 15, b = swz >> 9;

    float zfac = log1pf(expf(factor[0]));
    zfac = fminf(fmaxf(zfac, 0.0f), 0.001f);

    const int srow = tid >> 3, scol = (tid & 7) * 8;
    const int vkrow = tid & 63, vd0 = ((tid >> 6) & 7) * 8;

    const size_t qbase = ((size_t)(b * SCTX + q0)) * SD + h * 64;
#pragma unroll
    for (int g = 0; g < 2; ++g) {
        int row = srow + g * 32;
        *(u32x4*)&qs[row * 72 + scol] =
            *(const u32x4*)&qb[qbase + (size_t)row * SD + scol];
    }
    {
        const size_t kbase = ((size_t)(b * SCTX)) * SD + h * 64;
#pragma unroll
        for (int g = 0; g < 2; ++g) {
            int row = srow + g * 32;
            *(u32x4*)&ks[row * 72 + scol] =
                *(const u32x4*)&kb[kbase + (size_t)row * SD + scol];
        }
#pragma unroll
        for (int g = 0; g < 2; ++g) {
            int d8 = vd0 + g * 32;
            u32x4 vv = *(const u32x4*)&vb[kbase + (size_t)vkrow * SD + d8];
#pragma unroll
            for (int j = 0; j < 8; ++j) {
                unsigned uu = vv[j >> 1];
                u16 e = (j & 1) ? (u16)(uu >> 16) : (u16)(uu & 0xffffu);
                vts[(d8 + j) * 72 + vkrow] = e;
            }
        }
        if (tid < 64) {
            u16 k0v = kb[kbase + (size_t)tid * SD];
            zf[tid] = ((k0v & 0x7fffu) == 0) ? zfac : 1.0f;
        }
    }
    __syncthreads();
    bf16x8 aq0 = ldlds(&qs[(wave * 16 + l15) * 72 + lq * 8]);
    bf16x8 aq1 = ldlds(&qs[(wave * 16 + l15) * 72 + lq * 8 + 32]);

    f32x4 oacc[4];
#pragma unroll
    for (int t = 0; t < 4; ++t) oacc[t] = (f32x4){0.f, 0.f, 0.f, 0.f};
    float mrun[4], lrun[4];
#pragma unroll
    for (int r = 0; r < 4; ++r) { mrun[r] = -3.0e38f; lrun[r] = 0.0f; }

    const size_t qkrow0 = ((size_t)((b * 16 + h) * SCTX + q0)) * SCTX;

    for (int kt = 0; kt < 32; ++kt) {
        u32x4 pk0, pk1, pv0, pv1; u16 pz = 0;
        const bool pre = (kt + 1 < 32);
        if (pre) {
            const size_t kb1 = ((size_t)(b * SCTX + (kt + 1) * 64)) * SD + h * 64;
            pk0 = *(const u32x4*)&kb[kb1 + (size_t)srow * SD + scol];
            pk1 = *(const u32x4*)&kb[kb1 + (size_t)(srow + 32) * SD + scol];
            pv0 = *(const u32x4*)&vb[kb1 + (size_t)vkrow * SD + vd0];
            pv1 = *(const u32x4*)&vb[kb1 + (size_t)vkrow * SD + vd0 + 32];
            if (tid < 64) pz = kb[kb1 + (size_t)tid * SD];
        }

        f32x4 sacc[4];
#pragma unroll
        for (int t = 0; t < 4; ++t) sacc[t] = (f32x4){0.f, 0.f, 0.f, 0.f};
#pragma unroll
        for (int t = 0; t < 4; ++t) {
            bf16x8 bk0 = ldlds(&ks[(t * 16 + l15) * 72 + lq * 8]);
            bf16x8 bk1 = ldlds(&ks[(t * 16 + l15) * 72 + lq * 8 + 32]);
            sacc[t] = __builtin_amdgcn_mfma_f32_16x16x32_bf16(aq0, bk0, sacc[t], 0, 0, 0);
            sacc[t] = __builtin_amdgcn_mfma_f32_16x16x32_bf16(aq1, bk1, sacc[t], 0, 0, 0);
        }
        float zfc[4];
#pragma unroll
        for (int t = 0; t < 4; ++t) zfc[t] = zf[t * 16 + l15] * 0.125f;
#pragma unroll
        for (int t = 0; t < 4; ++t)
#pragma unroll
            for (int r = 0; r < 4; ++r) sacc[t][r] *= zfc[t];
#pragma unroll
        for (int t = 0; t < 4; ++t)
#pragma unroll
            for (int r = 0; r < 4; ++r) {
                int row = wave * 16 + lq * 4 + r;
                __builtin_nontemporal_store(sacc[t][r],
                    &qk_out[qkrow0 + (size_t)row * SCTX + kt * 64 + t * 16 + l15]);
            }
#pragma unroll
        for (int r = 0; r < 4; ++r) {
            float mx = fmaxf(fmaxf(sacc[0][r], sacc[1][r]),
                             fmaxf(sacc[2][r], sacc[3][r]));
            mx = fmaxf(mx, __shfl_xor(mx, 1, 64));
            mx = fmaxf(mx, __shfl_xor(mx, 2, 64));
            mx = fmaxf(mx, __shfl_xor(mx, 4, 64));
            mx = fmaxf(mx, __shfl_xor(mx, 8, 64));
            float mnew = fmaxf(mrun[r], mx);
            float alpha = __expf(mrun[r] - mnew);
            float p0 = __expf(sacc[0][r] - mnew);
            float p1 = __expf(sacc[1][r] - mnew);
            float p2 = __expf(sacc[2][r] - mnew);
            float p3 = __expf(sacc[3][r] - mnew);
            float rs = p0 + p1 + p2 + p3;
            rs += __shfl_xor(rs, 1, 64);
            rs += __shfl_xor(rs, 2, 64);
            rs += __shfl_xor(rs, 4, 64);
            rs += __shfl_xor(rs, 8, 64);
            lrun[r] = lrun[r] * alpha + rs;
            mrun[r] = mnew;
            int prow = (wave * 16 + lq * 4 + r) * 72;
            ps[prow + 0 + l15] = f2b(p0);
            ps[prow + 16 + l15] = f2b(p1);
            ps[prow + 32 + l15] = f2b(p2);
            ps[prow + 48 + l15] = f2b(p3);
#pragma unroll
            for (int td = 0; td < 4; ++td) oacc[td][r] *= alpha;
        }
        bf16x8 ap0 = ldlds(&ps[(wave * 16 + l15) * 72 + lq * 8]);
        bf16x8 ap1 = ldlds(&ps[(wave * 16 + l15) * 72 + lq * 8 + 32]);
#pragma unroll
        for (int td = 0; td < 4; ++td) {
            bf16x8 bv0 = ldlds(&vts[(td * 16 + l15) * 72 + lq * 8]);
            bf16x8 bv1 = ldlds(&vts[(td * 16 + l15) * 72 + lq * 8 + 32]);
            oacc[td] = __builtin_amdgcn_mfma_f32_16x16x32_bf16(ap0, bv0, oacc[td], 0, 0, 0);
            oacc[td] = __builtin_amdgcn_mfma_f32_16x16x32_bf16(ap1, bv1, oacc[td], 0, 0, 0);
        }

        __syncthreads();
        if (pre) {
            *(u32x4*)&ks[srow * 72 + scol] = pk0;
            *(u32x4*)&ks[(srow + 32) * 72 + scol] = pk1;
#pragma unroll
            for (int j = 0; j < 8; ++j) {
                unsigned uu = pv0[j >> 1];
                u16 e = (j & 1) ? (u16)(uu >> 16) : (u16)(uu & 0xffffu);
                vts[(vd0 + j) * 72 + vkrow] = e;
            }
#pragma unroll
            for (int j = 0; j < 8; ++j) {
                unsigned uu = pv1[j >> 1];
                u16 e = (j & 1) ? (u16)(uu >> 16) : (u16)(uu & 0xffffu);
                vts[(vd0 + 32 + j) * 72 + vkrow] = e;
            }
            if (tid < 64) zf[tid] = ((pz & 0x7fffu) == 0) ? zfac : 1.0f;
            __syncthreads();
        }
    }
    float linv[4];
#pragma unroll
    for (int r = 0; r < 4; ++r) linv[r] = 1.0f / lrun[r];
#pragma unroll
    for (int td = 0; td < 4; ++td)
#pragma unroll
        for (int r = 0; r < 4; ++r) {
            int row = wave * 16 + lq * 4 + r;
            wv_out[qbase + (size_t)row * SD + td * 16 + l15] =
                f2b(oacc[td][r] * linv[r]);
        }
}

// ---------------------------------------------------------------------------
// Launch. d_out: out fp32 (16.8MB) then qk fp32 (537MB). bf16 staging copies
// of x/Wq/Wk/Wv/Wout(+WoutT) live in the not-yet-written qk region (consumed
// before attn overwrites it). Projection paths:
//  - merged (ws >= 35.7MB): out = wv @ (Wout@Wout)^T-form + b2; wv/G/b2 in ws.
//  - fallback (ws >= 27.3MB): two GEMMs with bf16 Wout in ws.
//  - minimal: two GEMMs with fp32 Wout.
// ---------------------------------------------------------------------------
extern "C" void kernel_launch(void* const* d_in, const int* in_sizes, int n_in,
                              void* d_out, int out_size, void* d_ws, size_t ws_size,
                              hipStream_t stream)
{
    (void)in_sizes; (void)n_in; (void)out_size;
    const float* x      = (const float*)d_in[0];
    const float* Wq     = (const float*)d_in[1];
    const float* bq     = (const float*)d_in[2];
    const float* Wk     = (const float*)d_in[3];
    const float* Wv     = (const float*)d_in[4];
    const float* bvv    = (const float*)d_in[5];
    const float* Wout   = (const float*)d_in[6];
    const float* bout   = (const float*)d_in[7];
    const float* factor = (const float*)d_in[8];

    u16* ws   = (u16*)d_ws;
    u16* qbuf = ws;                   // 4194304 u16 each
    u16* kbuf = ws + 4194304;
    u16* vbuf = ws + 8388608;         // q/k/v end at byte 25,165,824
    u16* woutb = ws + 12582912;       // fallback: bf16 Wout (needs >= 27.3MB)
    u16* wvws  = ws + 12582912;       // merged: wv (8.4MB)
    u16* Gb    = ws + 16777216;       // merged: G = Wout@Wout bf16 (2MB)
    float* b2f = (float*)(ws + 17825792); // merged: fused bias (4KB)
    const bool merged      = ws_size >= (size_t)35655680;
    const bool have_woutb  = !merged && ws_size >= (size_t)27262976;

    float* outp = (float*)d_out;      // fp32 out (2,2048,1024)
    float* qkp  = outp + 4194304;     // fp32 qk (2,16,2048,2048)
    u16* wvo  = (u16*)d_out;          // fallback: wv staged in d_out
    u16* out1 = qbuf;                 // fallback: first projection (bf16)

    // bf16 staging copies in the (not-yet-written) qk region of d_out
    u16* xb   = (u16*)qkp;            // 4194304 u16
    u16* wqb  = xb + 4194304;         // 1048576 u16 each
    u16* wkb  = wqb + 1048576;
    u16* wvb  = wkb + 1048576;
    u16* wob  = wvb + 1048576;        // bf16 Wout (row-major)
    u16* wotb = wob + 1048576;        // bf16 Wout^T

    // Wout bf16 destination: ws copy for fallback path, qk region otherwise
    u16* wo_dst = have_woutb ? woutb : wob;

    cvt_all<<<4096, 256, 0, stream>>>(x, Wq, Wk, Wv, Wout,
                                      xb, wqb, wkb, wvb, wo_dst);

    dim3 gg(32, 16);  // 4096/128 x 1024/64

    gemm_bt_gl<u16><<<gg, 256, 0, stream>>>(xb, wqb, bq,      qbuf, 4096, 1024, 1024);
    gemm_bt_gl<u16><<<gg, 256, 0, stream>>>(xb, wkb, nullptr, kbuf, 4096, 1024, 1024);
    gemm_bt_gl<u16><<<gg, 256, 0, stream>>>(xb, wvb, bvv,     vbuf, 4096, 1024, 1024);

    if (merged) {
        // G = Wout @ Wout   (G[n][d] = sum_j Wout[n][j] * WoutT[d][j])
        cvt_bf16_t<<<dim3(32, 32), 256, 0, stream>>>(Wout, wotb);
        bias2_kernel<<<1024, 64, 0, stream>>>(Wout, bout, b2f);
        gemm_bt_gl<u16><<<dim3(8, 16), 256, 0, stream>>>(wob, wotb, nullptr,
                                                         Gb, 1024, 1024, 1024);
        attn_kernel<<<dim3(32, 16, 2), 256, 0, stream>>>(qbuf, kbuf, vbuf,
                                                         factor, qkp, wvws);
        // out = wv @ G^T(+b2): single projection replaces the double one
        gemm_bt_gl<float><<<gg, 256, 0, stream>>>(wvws, Gb, b2f, outp,
                                                  4096, 1024, 1024);
    } else {
        attn_kernel<<<dim3(32, 16, 2), 256, 0, stream>>>(qbuf, kbuf, vbuf,
                                                         factor, qkp, wvo);
        if (have_woutb) {
            gemm_bt_gl<u16><<<gg, 256, 0, stream>>>(wvo, woutb, bout, out1,
                                                    4096, 1024, 1024);
            gemm_bt_gl<float><<<gg, 256, 0, stream>>>(out1, woutb, bout, outp,
                                                      4096, 1024, 1024);
        } else {
            gemm_bt<u16, float, u16><<<gg, 256, 0, stream>>>(
                wvo, Wout, bout, out1, 4096, 1024, 1024);
            gemm_bt<u16, float, float><<<gg, 256, 0, stream>>>(
                out1, Wout, bout, outp, 4096, 1024, 1024);
        }
    }
}